// Round 1
// baseline (859.097 us; speedup 1.0000x reference)
//
#include <hip/hip_runtime.h>

// ---------------------------------------------------------------------------
// Workspace layout (fp32 elements):
//   h1   @ 0          : 256*16*16*16*16 = 16777216   (conv1+pool out)
//   c2   @ 16777216   : 256*32*8*8*8    = 4194304    (conv2 raw out)
//   feat @ 20971520   : 256*2048        = 524288
//   An   @ 21495808   : 4*64*64         = 16384
//   t1   @ 21512192   : 256*1024        = 262144     (feat@Wg1, atomics)
//   t2   @ 21774336   : 256*512         = 131072
//   t3   @ 21905408   : 256*256         = 65536
//   g1   @ 21970944   : 256*1024        = 262144
//   g2   @ 22233088   : 256*512         = 131072
//   g3   @ 22364160   : 256*256         = 65536
//   wl2  @ 22429696   : 432*32          = 13824      (conv2 weights relaid)
// total ~ 89.8 MB
// ---------------------------------------------------------------------------

// ---------------- K1: conv1 (1->16ch, 3x3x3, pad1) + maxpool3 s2 p1 --------
// One block per bn (256 blocks). Conv stage: thread (cy = t&31, chpair = t>>5)
// computes 32-wide conv rows for ch and ch+8 from global x (L1-hot), x-pools
// into LDS rowmax. Pool stage: thread (px = t&15, ch = t>>4) y-pools and keeps
// z-window parity accumulators in registers. bias+relu applied after max.
__global__ __launch_bounds__(256) void k_conv1_pool(
    const float* __restrict__ x, const float* __restrict__ wc,
    const float* __restrict__ bc, float* __restrict__ h1)
{
  const int bn = blockIdx.x;
  const int t  = threadIdx.x;
  __shared__ float rm[32 * 264 + 8];   // rm[cy*264 + ch*16 + px]
  const int cy = t & 31;
  const int c0 = t >> 5;               // channels c0 and c0+8
  const int ppx = t & 15;
  const int pch = t >> 4;
  float wA[27], wB[27];
#pragma unroll
  for (int k = 0; k < 27; ++k) { wA[k] = wc[c0 * 27 + k]; wB[k] = wc[(c0 + 8) * 27 + k]; }
  const float biasv = bc[pch];
  float accE[16], accO[16];
#pragma unroll
  for (int p = 0; p < 16; ++p) { accE[p] = -1e30f; accO[p] = -1e30f; }
  const float* xb = x + (size_t)bn * 32768;

#pragma unroll 1
  for (int cz = 0; cz < 32; ++cz) {
    // ---- conv rows for this z-plane ----
    float a0[32], a1[32];
#pragma unroll
    for (int xx = 0; xx < 32; ++xx) { a0[xx] = 0.f; a1[xx] = 0.f; }
#pragma unroll
    for (int p = 0; p < 3; ++p) {
      const int z = cz - 1 + p;
      if ((unsigned)z < 32u) {
#pragma unroll
        for (int dy = 0; dy < 3; ++dy) {
          const int yy = cy + dy - 1;
          if ((unsigned)yy < 32u) {
            const float* row = xb + (z << 10) + (yy << 5);
            float r[32];
#pragma unroll
            for (int q = 0; q < 8; ++q) {
              const float4 v = ((const float4*)row)[q];
              r[4*q] = v.x; r[4*q+1] = v.y; r[4*q+2] = v.z; r[4*q+3] = v.w;
            }
            const int wi = p * 9 + dy * 3;
            const float wa0 = wA[wi], wa1 = wA[wi+1], wa2 = wA[wi+2];
            const float wb0 = wB[wi], wb1 = wB[wi+1], wb2 = wB[wi+2];
            a0[0] += wa1 * r[0] + wa2 * r[1];
            a1[0] += wb1 * r[0] + wb2 * r[1];
#pragma unroll
            for (int xx = 1; xx < 31; ++xx) {
              a0[xx] += wa0 * r[xx-1] + wa1 * r[xx] + wa2 * r[xx+1];
              a1[xx] += wb0 * r[xx-1] + wb1 * r[xx] + wb2 * r[xx+1];
            }
            a0[31] += wa0 * r[30] + wa1 * r[31];
            a1[31] += wb0 * r[30] + wb1 * r[31];
          }
        }
      }
    }
    // ---- x-pool (stride 2, window 3, pad) -> rm ----
    {
      float* rA = &rm[cy * 264 + c0 * 16];
      float* rB = &rm[cy * 264 + (c0 + 8) * 16];
      rA[0] = fmaxf(a0[0], a0[1]);
      rB[0] = fmaxf(a1[0], a1[1]);
#pragma unroll
      for (int px = 1; px < 16; ++px) {
        rA[px] = fmaxf(fmaxf(a0[2*px-1], a0[2*px]), a0[2*px+1]);
        rB[px] = fmaxf(fmaxf(a1[2*px-1], a1[2*px]), a1[2*px+1]);
      }
    }
    __syncthreads();
    // ---- y-pool + rolling z-pool ----
    const int plo = (cz - 1) >> 1;       // closes at odd cz
    const int phi = (cz + 1) >> 1;
    const bool odd = (cz & 1) != 0;
#pragma unroll
    for (int py = 0; py < 16; ++py) {
      float v = -1e30f;
#pragma unroll
      for (int dy = 0; dy < 3; ++dy) {
        const int yy = 2 * py - 1 + dy;
        if ((unsigned)yy < 32u) v = fmaxf(v, rm[yy * 264 + pch * 16 + ppx]);
      }
      if (odd) {
        if ((plo & 1) == 0) accE[py] = fmaxf(accE[py], v);
        else                accO[py] = fmaxf(accO[py], v);
        if (phi < 16) {
          if ((phi & 1) == 0) accE[py] = fmaxf(accE[py], v);
          else                accO[py] = fmaxf(accO[py], v);
        }
      } else {
        if ((phi & 1) == 0) accE[py] = fmaxf(accE[py], v);
        else                accO[py] = fmaxf(accO[py], v);
      }
    }
    if (odd) {   // pooled plane pz = plo complete
      float* op = h1 + (((size_t)(bn * 16 + pch) * 16 + plo) << 8) + ppx;
      if ((plo & 1) == 0) {
#pragma unroll
        for (int py = 0; py < 16; ++py) { op[py * 16] = fmaxf(accE[py] + biasv, 0.f); accE[py] = -1e30f; }
      } else {
#pragma unroll
        for (int py = 0; py < 16; ++py) { op[py * 16] = fmaxf(accO[py] + biasv, 0.f); accO[py] = -1e30f; }
      }
    }
    __syncthreads();   // rm fully consumed before next plane overwrites
  }
}

// ---------------- conv2 weight relayout: wl2[(ic,dz,dy,dx)][ch] ------------
__global__ void k_w2_relayout(const float* __restrict__ w2, float* __restrict__ wl2)
{
  const int tid = blockIdx.x * 256 + threadIdx.x;   // 13824
  if (tid < 13824) {
    const int ch = tid & 31, rest = tid >> 5;       // rest 0..431
    const int ic = rest / 27, k = rest % 27;
    wl2[tid] = w2[ch * 432 + ic * 27 + k];
  }
}

// ---------------- K2: conv2 (16->32ch, 3x3x3, stride2, pad1), raw out ------
// grid 2048 = (bn, oz); 64 threads: chq = t>>3 (4 ch), oy = t&7, ox unrolled.
__global__ __launch_bounds__(64) void k_conv2(
    const float* __restrict__ h1, const float* __restrict__ wl2, float* __restrict__ c2)
{
  const int bn = blockIdx.x >> 3, oz = blockIdx.x & 7;
  const int t = threadIdx.x;
  const int chq = t >> 3;
  const int oy  = t & 7;
  float acc[4][8];
#pragma unroll
  for (int j = 0; j < 4; ++j)
#pragma unroll
    for (int o = 0; o < 8; ++o) acc[j][o] = 0.f;
  const float* hb = h1 + ((size_t)bn << 16);
#pragma unroll 1
  for (int ic = 0; ic < 16; ++ic) {
    const float* plane = hb + (ic << 12);
#pragma unroll
    for (int dz = 0; dz < 3; ++dz) {
      const int iz = 2 * oz - 1 + dz;
      if ((unsigned)iz < 16u) {
#pragma unroll
        for (int dy = 0; dy < 3; ++dy) {
          const int iy = 2 * oy - 1 + dy;
          if ((unsigned)iy < 16u) {
            const float* row = plane + (iz << 8) + (iy << 4);
            float rr[17];
            rr[0] = 0.f;                      // x = -1 pad
#pragma unroll
            for (int q = 0; q < 4; ++q) {
              const float4 v = ((const float4*)row)[q];
              rr[4*q+1] = v.x; rr[4*q+2] = v.y; rr[4*q+3] = v.z; rr[4*q+4] = v.w;
            }
            const float* wb = wl2 + (size_t)((ic * 9 + dz * 3 + dy) * 3) * 32 + chq * 4;
#pragma unroll
            for (int dx = 0; dx < 3; ++dx) {
              const float4 w4 = *(const float4*)(wb + dx * 32);
#pragma unroll
              for (int o = 0; o < 8; ++o) {
                const float xv = rr[2 * o + dx];   // input x = 2*o - 1 + dx
                acc[0][o] += xv * w4.x;
                acc[1][o] += xv * w4.y;
                acc[2][o] += xv * w4.z;
                acc[3][o] += xv * w4.w;
              }
            }
          }
        }
      }
    }
  }
#pragma unroll
  for (int j = 0; j < 4; ++j) {
    const int ch = chq * 4 + j;
    float* dst = c2 + (((size_t)(bn * 32 + ch) * 8 + oz) << 6) + (oy << 3);
    *(float4*)dst       = make_float4(acc[j][0], acc[j][1], acc[j][2], acc[j][3]);
    *(float4*)(dst + 4) = make_float4(acc[j][4], acc[j][5], acc[j][6], acc[j][7]);
  }
}

// ---------------- K2b: maxpool3 s2 p1 + bias + relu -> feat ----------------
__global__ void k_pool2(const float* __restrict__ c2, const float* __restrict__ bc2,
                        float* __restrict__ feat)
{
  const int tid = blockIdx.x * 256 + threadIdx.x;  // 524288
  const int bn = tid >> 11, f = tid & 2047;
  const int ch = f >> 6, pz = (f >> 4) & 3, py = (f >> 2) & 3, px = f & 3;
  const float* base = c2 + ((size_t)(bn * 32 + ch) << 9);
  float m = -1e30f;
#pragma unroll
  for (int dz = 0; dz < 3; ++dz) {
    const int oz = 2 * pz - 1 + dz;
    if ((unsigned)oz < 8u) {
#pragma unroll
      for (int dy = 0; dy < 3; ++dy) {
        const int oy = 2 * py - 1 + dy;
        if ((unsigned)oy < 8u) {
#pragma unroll
          for (int dx = 0; dx < 3; ++dx) {
            const int ox = 2 * px - 1 + dx;
            if ((unsigned)ox < 8u) m = fmaxf(m, base[(oz << 6) + (oy << 3) + ox]);
          }
        }
      }
    }
  }
  feat[tid] = fmaxf(m + bc2[ch], 0.f);
}

// ---------------- A_norm = D^-1/2 (A+I) D^-1/2 -----------------------------
__global__ __launch_bounds__(64) void k_gcn_norm(const int* __restrict__ adj, float* __restrict__ An)
{
  const int b = blockIdx.x, i = threadIdx.x;
  __shared__ float dinv[64];
  const int* ab = adj + b * 4096;
  int deg = 1;
  for (int j = 0; j < 64; ++j) deg += (ab[i * 64 + j] != 0) ? 1 : 0;
  dinv[i] = rsqrtf((float)deg);
  __syncthreads();
  const float di = dinv[i];
  for (int j = 0; j < 64; ++j) {
    const float a = (i == j) ? 1.f : ((ab[i * 64 + j] != 0) ? 1.f : 0.f);
    An[b * 4096 + i * 64 + j] = a * di * dinv[j];
  }
}

// ---------------- zero a region -------------------------------------------
__global__ void k_zero(float* __restrict__ p, int n)
{
  const int tid = blockIdx.x * 256 + threadIdx.x;
  if (tid < n) p[tid] = 0.f;
}

// ---------------- fp32 GEMM, 64x64 tile, K-split + atomicAdd ---------------
// grid (N/64, M/64, S); block 256; C must be zeroed.
__global__ __launch_bounds__(256) void k_gemm_ksplit(
    const float* __restrict__ A, const float* __restrict__ B, float* __restrict__ C,
    int M, int N, int K, int klen)
{
  (void)M;
  const int jb = blockIdx.x << 6;
  const int ib = blockIdx.y << 6;
  const int k0 = blockIdx.z * klen;
  __shared__ float As[16 * 64];
  __shared__ float Bs[16 * 64];
  const int t = threadIdx.x;
  const int ti = t & 15, tj = t >> 4;
  const int li = t >> 2, lk = t & 3;
  const int bk = t >> 4, bj = t & 15;
  float acc[4][4];
#pragma unroll
  for (int u = 0; u < 4; ++u)
#pragma unroll
    for (int v = 0; v < 4; ++v) acc[u][v] = 0.f;
#pragma unroll 1
  for (int kt = 0; kt < klen; kt += 16) {
    __syncthreads();
    {
      const float4 av = *(const float4*)&A[(size_t)(ib + li) * K + k0 + kt + 4 * lk];
      As[(4*lk+0)*64 + li] = av.x;
      As[(4*lk+1)*64 + li] = av.y;
      As[(4*lk+2)*64 + li] = av.z;
      As[(4*lk+3)*64 + li] = av.w;
      const float4 bv = *(const float4*)&B[(size_t)(k0 + kt + bk) * N + jb + 4 * bj];
      *(float4*)&Bs[bk * 64 + 4 * bj] = bv;
    }
    __syncthreads();
#pragma unroll
    for (int k = 0; k < 16; ++k) {
      const float4 a = *(const float4*)&As[k * 64 + 4 * ti];
      const float4 b = *(const float4*)&Bs[k * 64 + 4 * tj];
      acc[0][0] += a.x*b.x; acc[0][1] += a.x*b.y; acc[0][2] += a.x*b.z; acc[0][3] += a.x*b.w;
      acc[1][0] += a.y*b.x; acc[1][1] += a.y*b.y; acc[1][2] += a.y*b.z; acc[1][3] += a.y*b.w;
      acc[2][0] += a.z*b.x; acc[2][1] += a.z*b.y; acc[2][2] += a.z*b.z; acc[2][3] += a.z*b.w;
      acc[3][0] += a.w*b.x; acc[3][1] += a.w*b.y; acc[3][2] += a.w*b.z; acc[3][3] += a.w*b.w;
    }
  }
#pragma unroll
  for (int u = 0; u < 4; ++u) {
    float* crow = C + (size_t)(ib + 4 * ti + u) * N + jb + 4 * tj;
    atomicAdd(crow + 0, acc[u][0]);
    atomicAdd(crow + 1, acc[u][1]);
    atomicAdd(crow + 2, acc[u][2]);
    atomicAdd(crow + 3, acc[u][3]);
  }
}

// ---------------- G = (An_b @ T_b) + bias (+relu), per graph ---------------
// grid (F/64, 4); block 256.
__global__ __launch_bounds__(256) void k_graph_mm(
    const float* __restrict__ An, const float* __restrict__ T,
    const float* __restrict__ bias, float* __restrict__ G, int F, int relu)
{
  const int b = blockIdx.y;
  const int f0 = blockIdx.x << 6;
  __shared__ float Ans[64 * 65];
  __shared__ float Ts[64 * 64];
  const int t = threadIdx.x;
  for (int idx = t; idx < 4096; idx += 256)
    Ans[(idx >> 6) * 65 + (idx & 63)] = An[b * 4096 + idx];
  for (int idx = t; idx < 1024; idx += 256) {
    const int j = idx >> 4, q = idx & 15;
    *(float4*)&Ts[j * 64 + 4 * q] = *(const float4*)&T[(size_t)(b * 64 + j) * F + f0 + 4 * q];
  }
  __syncthreads();
  const int i = t >> 2, fq = t & 3;
  float acc[16];
#pragma unroll
  for (int u = 0; u < 16; ++u) acc[u] = 0.f;
#pragma unroll 1
  for (int j = 0; j < 64; ++j) {
    const float aij = Ans[i * 65 + j];
    const float* tr = &Ts[j * 64 + fq * 16];
#pragma unroll
    for (int u = 0; u < 16; ++u) acc[u] += aij * tr[u];
  }
  float* gr = G + (size_t)(b * 64 + i) * F + f0 + fq * 16;
  const float* br = bias + f0 + fq * 16;
#pragma unroll
  for (int u = 0; u < 16; ++u) {
    const float v = acc[u] + br[u];
    gr[u] = relu ? fmaxf(v, 0.f) : v;
  }
}

// ---------------- head: chunk-max + fc1 + relu + fc2 + softmax -------------
__global__ __launch_bounds__(256) void k_head(
    const float* __restrict__ g3, const float* __restrict__ w1, const float* __restrict__ b1,
    const float* __restrict__ w2, const float* __restrict__ b2, float* __restrict__ out)
{
  const int b = blockIdx.x, t = threadIdx.x;
  __shared__ float sp[256];
  __shared__ float sh[512];
  __shared__ float sl[4];
  {
    const int n = t >> 2, c = t & 3;
    const float* gr = g3 + (size_t)(b * 64 + n) * 256 + c * 64;
    float m = -1e30f;
    for (int f = 0; f < 64; ++f) m = fmaxf(m, gr[f]);
    sp[t] = m;   // pooled[b, n*4+c]
  }
  __syncthreads();
  for (int jj = t; jj < 512; jj += 256) {
    float s = b1[jj];
    for (int k = 0; k < 256; ++k) s += sp[k] * w1[k * 512 + jj];
    sh[jj] = fmaxf(s, 0.f);
  }
  __syncthreads();
  if (t < 4) {
    float s = b2[t];
    for (int k = 0; k < 512; ++k) s += sh[k] * w2[k * 4 + t];
    sl[t] = s;
  }
  __syncthreads();
  if (t == 0) {
    const float m = fmaxf(fmaxf(sl[0], sl[1]), fmaxf(sl[2], sl[3]));
    const float e0 = expf(sl[0] - m), e1 = expf(sl[1] - m);
    const float e2 = expf(sl[2] - m), e3 = expf(sl[3] - m);
    const float inv = 1.f / (e0 + e1 + e2 + e3);
    out[b * 4 + 0] = e0 * inv;
    out[b * 4 + 1] = e1 * inv;
    out[b * 4 + 2] = e2 * inv;
    out[b * 4 + 3] = e3 * inv;
  }
}

// ---------------------------------------------------------------------------
extern "C" void kernel_launch(void* const* d_in, const int* in_sizes, int n_in,
                              void* d_out, int out_size, void* d_ws, size_t ws_size,
                              hipStream_t stream)
{
  (void)in_sizes; (void)n_in; (void)out_size; (void)ws_size;
  const float* x   = (const float*)d_in[0];
  const int*   adj = (const int*)d_in[1];
  const float* wc1 = (const float*)d_in[3];
  const float* bc1 = (const float*)d_in[4];
  const float* wc2 = (const float*)d_in[5];
  const float* bc2 = (const float*)d_in[6];
  const float* wg1 = (const float*)d_in[7];
  const float* bg1 = (const float*)d_in[8];
  const float* wg2 = (const float*)d_in[9];
  const float* bg2 = (const float*)d_in[10];
  const float* wg3 = (const float*)d_in[11];
  const float* bg3 = (const float*)d_in[12];
  const float* wf1 = (const float*)d_in[13];
  const float* bf1 = (const float*)d_in[14];
  const float* wf2 = (const float*)d_in[15];
  const float* bf2 = (const float*)d_in[16];

  float* ws   = (float*)d_ws;
  float* h1   = ws;
  float* c2   = ws + 16777216;
  float* feat = ws + 20971520;
  float* An   = ws + 21495808;
  float* t1   = ws + 21512192;
  float* t2   = ws + 21774336;
  float* t3   = ws + 21905408;
  float* g1   = ws + 21970944;
  float* g2   = ws + 22233088;
  float* g3   = ws + 22364160;
  float* wl2  = ws + 22429696;
  float* outp = (float*)d_out;

  hipLaunchKernelGGL(k_zero,        dim3(1792),    dim3(256), 0, stream, t1, 458752); // t1..t3
  hipLaunchKernelGGL(k_w2_relayout, dim3(54),      dim3(256), 0, stream, wc2, wl2);
  hipLaunchKernelGGL(k_conv1_pool,  dim3(256),     dim3(256), 0, stream, x, wc1, bc1, h1);
  hipLaunchKernelGGL(k_conv2,       dim3(2048),    dim3(64),  0, stream, h1, wl2, c2);
  hipLaunchKernelGGL(k_pool2,       dim3(2048),    dim3(256), 0, stream, c2, bc2, feat);
  hipLaunchKernelGGL(k_gcn_norm,    dim3(4),       dim3(64),  0, stream, adj, An);
  hipLaunchKernelGGL(k_gemm_ksplit, dim3(16,4,4),  dim3(256), 0, stream, feat, wg1, t1, 256, 1024, 2048, 512);
  hipLaunchKernelGGL(k_graph_mm,    dim3(16,4),    dim3(256), 0, stream, An, t1, bg1, g1, 1024, 1);
  hipLaunchKernelGGL(k_gemm_ksplit, dim3(8,4,8),   dim3(256), 0, stream, g1, wg2, t2, 256, 512, 1024, 128);
  hipLaunchKernelGGL(k_graph_mm,    dim3(8,4),     dim3(256), 0, stream, An, t2, bg2, g2, 512, 1);
  hipLaunchKernelGGL(k_gemm_ksplit, dim3(4,4,16),  dim3(256), 0, stream, g2, wg3, t3, 256, 256, 512, 32);
  hipLaunchKernelGGL(k_graph_mm,    dim3(4,4),     dim3(256), 0, stream, An, t3, bg3, g3, 256, 0);
  hipLaunchKernelGGL(k_head,        dim3(4),       dim3(256), 0, stream, g3, wf1, bf1, wf2, bf2, outp);
}